// Round 5
// baseline (715.244 us; speedup 1.0000x reference)
//
#include <hip/hip_runtime.h>
#include <hip/hip_bf16.h>
#include <math.h>

#define B_SZ 32
#define VLEN_SZ 2048
#define H_SZ 1024
#define DIM_SZ 1024
#define C_SZ 32

typedef float f32x4 __attribute__((ext_vector_type(4)));
typedef float f32x16 __attribute__((ext_vector_type(16)));
typedef short s16x8 __attribute__((ext_vector_type(8)));
typedef short s16x4 __attribute__((ext_vector_type(4)));
typedef unsigned int u32x4 __attribute__((ext_vector_type(4)));

__device__ __forceinline__ short f2bf(float f) {
  unsigned u = __float_as_uint(f);
  u = (u + 0x7fffu + ((u >> 16) & 1u)) >> 16;  // RNE
  return (short)u;
}

__device__ __forceinline__ float bf2f(short s) {
  return __uint_as_float(((unsigned)(unsigned short)s) << 16);
}

// pack hi16(a), hi16(b) -> (bf16(b)<<16)|bf16(a)  [truncation], 1 instr
__device__ __forceinline__ unsigned pack2(float a, float b) {
  return __builtin_amdgcn_perm(__float_as_uint(b), __float_as_uint(a), 0x07060302u);
}

__device__ __forceinline__ float fast_tanh(float x) {
  float z = __expf(2.0f * x);
  return 1.0f - 2.0f / (z + 1.0f);
}

// async 16B global -> LDS. LDS base MUST be wave-uniform (HW adds lane*16).
__device__ __forceinline__ void ldg_lds16(const void* g, void* l) {
  __builtin_amdgcn_global_load_lds(
      (const __attribute__((address_space(1))) unsigned int*)g,
      (__attribute__((address_space(3))) unsigned int*)l, 16, 0, 0);
}

// ---- fused prep: qpb + conv-features(bf16) + weight casts + value->bf16 ----
// role by block range:
//   [0,256)        qp[b,d]: one WAVE per d, loop over b (w_q read exactly once)
//   [256,512)      conv features cfb[b,v,c] bf16
//   [512,544)      w_loc -> bf16
//   [544,1568)     w_v   -> bf16
//   [1568,1632)    zero score
//   [1632,1664)    zero context
//   [1664,34432)   value -> bf16 (8 floats/thread, s16x8 stores)
__global__ __launch_bounds__(256) void k_prep(
    const float* __restrict__ query, const float* __restrict__ w_q,
    const float* __restrict__ bias, const float* __restrict__ prev,
    const float* __restrict__ conv_w, const float* __restrict__ conv_b,
    const float* __restrict__ w_loc, const float* __restrict__ w_v,
    const float* __restrict__ value,
    float* __restrict__ qpb, short* __restrict__ cfb, short* __restrict__ wlocb,
    short* __restrict__ wvb, short* __restrict__ vb,
    float* __restrict__ score, float* __restrict__ context) {
  int bid = blockIdx.x;
  int t = threadIdx.x;
  if (bid < 256) {
    int d = bid * 4 + (t >> 6);      // one wave per output column d
    int l = t & 63;
    const f32x4* w4 = (const f32x4*)(w_q + (size_t)d * H_SZ);
    f32x4 wq[4];
#pragma unroll
    for (int it = 0; it < 4; ++it) wq[it] = w4[it * 64 + l];
    float bd = bias[d];
    for (int b = 0; b < B_SZ; ++b) {
      const f32x4* q4 = (const f32x4*)(query + (size_t)b * H_SZ);
      float acc = 0.f;
#pragma unroll
      for (int it = 0; it < 4; ++it) {
        f32x4 a = q4[it * 64 + l];
        acc += a[0] * wq[it][0] + a[1] * wq[it][1] + a[2] * wq[it][2] + a[3] * wq[it][3];
      }
#pragma unroll
      for (int off = 32; off; off >>= 1) acc += __shfl_xor(acc, off, 64);
      if (l == 0) qpb[(size_t)b * DIM_SZ + d] = acc + bd;
    }
  } else if (bid < 512) {
    int r = (bid - 256) * 256 + t;  // row index b*VLEN+v
    int v = r & (VLEN_SZ - 1);
    float p0 = prev[r];
    float pm = (v > 0) ? prev[r - 1] : 0.f;
    float pp = (v < VLEN_SZ - 1) ? prev[r + 1] : 0.f;
    float o[C_SZ];
#pragma unroll
    for (int c = 0; c < C_SZ; ++c)
      o[c] = conv_b[c] + pm * conv_w[c * 3 + 0] + p0 * conv_w[c * 3 + 1] + pp * conv_w[c * 3 + 2];
    s16x8* dst = (s16x8*)(cfb + (size_t)r * C_SZ);
#pragma unroll
    for (int g = 0; g < 4; ++g) {
      s16x8 pk;
#pragma unroll
      for (int e = 0; e < 8; ++e) pk[e] = f2bf(o[8 * g + e]);
      dst[g] = pk;
    }
  } else if (bid < 544) {
    int i = (bid - 512) * 256 + t;  // n4 = 8192
    f32x4 v = ((const f32x4*)w_loc)[i];
    s16x4 o;
    o[0] = f2bf(v[0]); o[1] = f2bf(v[1]); o[2] = f2bf(v[2]); o[3] = f2bf(v[3]);
    ((s16x4*)wlocb)[i] = o;
  } else if (bid < 1568) {
    int i = (bid - 544) * 256 + t;  // n4 = 262144
    f32x4 v = ((const f32x4*)w_v)[i];
    s16x4 o;
    o[0] = f2bf(v[0]); o[1] = f2bf(v[1]); o[2] = f2bf(v[2]); o[3] = f2bf(v[3]);
    ((s16x4*)wvb)[i] = o;
  } else if (bid < 1632) {
    int i = (bid - 1568) * 256 + t;  // 16384 f32x4
    ((f32x4*)score)[i] = (f32x4){0.f, 0.f, 0.f, 0.f};
  } else if (bid < 1664) {
    int i = (bid - 1632) * 256 + t;  // 8192 f32x4
    ((f32x4*)context)[i] = (f32x4){0.f, 0.f, 0.f, 0.f};
  } else {
    // value (fp32, 67.1M) -> bf16. 8 floats/thread: read 32B, write 16B.
    size_t i = (size_t)(bid - 1664) * 256 + t;  // 0 .. 8388607
    const f32x4* src = (const f32x4*)value;
    f32x4 v0 = src[2 * i], v1 = src[2 * i + 1];
    s16x8 o;
    o[0] = f2bf(v0[0]); o[1] = f2bf(v0[1]); o[2] = f2bf(v0[2]); o[3] = f2bf(v0[3]);
    o[4] = f2bf(v1[0]); o[5] = f2bf(v1[1]); o[6] = f2bf(v1[2]); o[7] = f2bf(v1[3]);
    ((s16x8*)vb)[i] = o;
  }
}

// ==== main fused kernel: 128x128 tile, BK=32, 4 waves, 32x32x16 MFMA ====
// Proven round-1 2-syncthreads structure; geometry changed to cut the LDS
// pole: 8 ds_read_b128 + 8 MFMA(32K FLOP) per wave-tile vs 12 reads + 16
// MFMA(16K). LDS chunk-column layout: 16B slot index = chunk*128 + row
// (chunk = 8 bf16 of K). Staged by global_load_lds with wave-uniform LDS
// base (wave w owns chunk c=w; lane l -> row rh*64+l), so frag reads
// (lanes 0..31 -> consecutive rows = consecutive slots) are conflict-free.
// 33 K-tiles: 32 of vb/wvb + 1 of cfb/wlocb (32-col rows = one BK tile).
// A-frag (32x32x16): lane holds m=l&31, k=(l>>5)*8..+7 -> slot (ks*2+(l>>5))*128+row.
// C/D: col(d)=lane&31, row(v)=(reg&3)+8*(reg>>2)+4*(lane>>5)  [m74/m101].
__global__ __launch_bounds__(256, 4) void k_score32(
    const short* __restrict__ vb, const short* __restrict__ wvb,
    const short* __restrict__ wlocb, const short* __restrict__ cfb,
    const float* __restrict__ qpb, const float* __restrict__ w_score,
    float* __restrict__ score) {
  __shared__ short As[4096];   // 8 KB: slot c*128+r, 8 bf16/slot
  __shared__ short Bs[4096];   // 8 KB
  __shared__ float sred[4][64];

  int t = threadIdx.x;
  int w = t >> 6, l = t & 63;
  int l32 = l & 31, hi = l >> 5;
  int bid = blockIdx.x;
  int x = bid & 7;
  int j = bid >> 3;
  int nt = j & 7;                  // 0..7
  int mt = x * 64 + (j >> 3);      // 0..511
  int row0 = mt * 128;             // global row base (b*VLEN+v)
  int d0 = nt * 128;
  int b = row0 >> 11;              // VLEN = 2048
  int wm = w >> 1, wn = w & 1;

  // staging: wave w owns chunk c=w. Instr rh in {0,1}: lane l -> global row
  // rh*64+l, k-bytes [kt*64 + c*16, +16). LDS dest (uniform): slot c*128+rh*64.
  const short* gA = vb + (size_t)(row0 + l) * H_SZ + w * 8;
  const short* gB = wvb + (size_t)(d0 + l) * H_SZ + w * 8;
  const short* gAc = cfb + (size_t)(row0 + l) * C_SZ + w * 8;
  const short* gBc = wlocb + (size_t)(d0 + l) * C_SZ + w * 8;
  short* lA0 = As + (w * 128) * 8;
  short* lA1 = As + (w * 128 + 64) * 8;
  short* lB0 = Bs + (w * 128) * 8;
  short* lB1 = Bs + (w * 128 + 64) * 8;
  size_t rstep = (size_t)64 * H_SZ;   // 64 rows
  size_t rstepc = (size_t)64 * C_SZ;

  f32x16 acc[2][2];
#pragma unroll
  for (int mi = 0; mi < 2; ++mi)
#pragma unroll
    for (int nj = 0; nj < 2; ++nj)
#pragma unroll
      for (int r = 0; r < 16; ++r) acc[mi][nj][r] = 0.f;

  for (int kt = 0; kt <= 32; ++kt) {
    if (kt < 32) {
      size_t k0 = (size_t)kt * 32;
      ldg_lds16(gA + k0, lA0);
      ldg_lds16(gA + k0 + rstep, lA1);
      ldg_lds16(gB + k0, lB0);
      ldg_lds16(gB + k0 + rstep, lB1);
    } else {
      ldg_lds16(gAc, lA0);
      ldg_lds16(gAc + rstepc, lA1);
      ldg_lds16(gBc, lB0);
      ldg_lds16(gBc + rstepc, lB1);
    }
    __syncthreads();

    s16x8 af[2][2], bf[2][2];   // [tile][k-slice]
#pragma unroll
    for (int mi = 0; mi < 2; ++mi)
#pragma unroll
      for (int ks = 0; ks < 2; ++ks) {
        int c = ks * 2 + hi;
        af[mi][ks] = *(const s16x8*)(As + (c * 128 + wm * 64 + mi * 32 + l32) * 8);
        bf[mi][ks] = *(const s16x8*)(Bs + (c * 128 + wn * 64 + mi * 32 + l32) * 8);
      }
#pragma unroll
    for (int ks = 0; ks < 2; ++ks)
#pragma unroll
      for (int mi = 0; mi < 2; ++mi)
#pragma unroll
        for (int nj = 0; nj < 2; ++nj)
          acc[mi][nj] = __builtin_amdgcn_mfma_f32_32x32x16_bf16(
              af[mi][ks], bf[nj][ks], acc[mi][nj], 0, 0, 0);
    __syncthreads();
  }

  // epilogue: e = tanh(acc + qp[d]) (qp includes bias), score += e.w_score
  float qv[2], wv[2];
#pragma unroll
  for (int nj = 0; nj < 2; ++nj) {
    int d = d0 + wn * 64 + nj * 32 + l32;
    qv[nj] = qpb[(size_t)b * DIM_SZ + d];
    wv[nj] = w_score[d];
  }

#pragma unroll
  for (int mi = 0; mi < 2; ++mi) {
#pragma unroll
    for (int r = 0; r < 16; ++r) {
      float part = fast_tanh(acc[mi][0][r] + qv[0]) * wv[0] +
                   fast_tanh(acc[mi][1][r] + qv[1]) * wv[1];
      part += __shfl_xor(part, 1);
      part += __shfl_xor(part, 2);
      part += __shfl_xor(part, 4);
      part += __shfl_xor(part, 8);
      part += __shfl_xor(part, 16);
      if (l32 == 0) {
        int rowin = mi * 32 + (r & 3) + 8 * (r >> 2) + 4 * hi;  // 0..63
        sred[w][rowin] = part;
      }
    }
  }
  __syncthreads();
  if (t < 128) {
    int half = t >> 6;
    float v = sred[half * 2][t & 63] + sred[half * 2 + 1][t & 63];
    atomicAdd(&score[row0 + t], v);
  }
}

// ================= fallback path (small workspace): previous proven kernels =================
__global__ __launch_bounds__(256) void k_prep_f32(
    const float* __restrict__ query, const float* __restrict__ w_q,
    const float* __restrict__ bias, const float* __restrict__ prev,
    const float* __restrict__ conv_w, const float* __restrict__ conv_b,
    const float* __restrict__ w_loc, const float* __restrict__ w_v,
    float* __restrict__ qpb, float* __restrict__ cff, short* __restrict__ wlocb,
    short* __restrict__ wvb, float* __restrict__ score, float* __restrict__ context) {
  int bid = blockIdx.x;
  int t = threadIdx.x;
  if (bid < 8192) {
    int wid = bid * 4 + (t >> 6);
    int lane = t & 63;
    int d = wid >> 5;
    int b = wid & 31;
    const f32x4* q4 = (const f32x4*)(query + (size_t)b * H_SZ);
    const f32x4* w4 = (const f32x4*)(w_q + (size_t)d * H_SZ);
    float acc = 0.f;
#pragma unroll
    for (int it = 0; it < 4; ++it) {
      int k = it * 64 + lane;
      f32x4 a = q4[k], w = w4[k];
      acc += a[0] * w[0] + a[1] * w[1] + a[2] * w[2] + a[3] * w[3];
    }
#pragma unroll
    for (int off = 32; off; off >>= 1) acc += __shfl_xor(acc, off, 64);
    if (lane == 0) qpb[(size_t)b * DIM_SZ + d] = acc + bias[d];
  } else if (bid < 8448) {
    int r = (bid - 8192) * 256 + t;
    int v = r & (VLEN_SZ - 1);
    float p0 = prev[r];
    float pm = (v > 0) ? prev[r - 1] : 0.f;
    float pp = (v < VLEN_SZ - 1) ? prev[r + 1] : 0.f;
    float o[C_SZ];
#pragma unroll
    for (int c = 0; c < C_SZ; ++c)
      o[c] = conv_b[c] + pm * conv_w[c * 3 + 0] + p0 * conv_w[c * 3 + 1] + pp * conv_w[c * 3 + 2];
    f32x4* dst = (f32x4*)(cff + (size_t)r * C_SZ);
#pragma unroll
    for (int g = 0; g < 8; ++g)
      dst[g] = (f32x4){o[4 * g], o[4 * g + 1], o[4 * g + 2], o[4 * g + 3]};
  } else if (bid < 8480) {
    int i = (bid - 8448) * 256 + t;
    f32x4 v = ((const f32x4*)w_loc)[i];
    s16x4 o;
    o[0] = f2bf(v[0]); o[1] = f2bf(v[1]); o[2] = f2bf(v[2]); o[3] = f2bf(v[3]);
    ((s16x4*)wlocb)[i] = o;
  } else if (bid < 9504) {
    int i = (bid - 8480) * 256 + t;
    f32x4 v = ((const f32x4*)w_v)[i];
    s16x4 o;
    o[0] = f2bf(v[0]); o[1] = f2bf(v[1]); o[2] = f2bf(v[2]); o[3] = f2bf(v[3]);
    ((s16x4*)wvb)[i] = o;
  } else if (bid < 9568) {
    int i = (bid - 9504) * 256 + t;
    ((f32x4*)score)[i] = (f32x4){0.f, 0.f, 0.f, 0.f};
  } else {
    int i = (bid - 9568) * 256 + t;
    ((f32x4*)context)[i] = (f32x4){0.f, 0.f, 0.f, 0.f};
  }
}

__global__ __launch_bounds__(256, 4) void k_score_f32(
    const float* __restrict__ value, const short* __restrict__ wvb,
    const short* __restrict__ wlocb, const float* __restrict__ cff,
    const float* __restrict__ qpb, const float* __restrict__ w_score,
    float* __restrict__ score) {
  __shared__ float Asf[128 * 32];
  __shared__ short Bsf[128 * 32];
  __shared__ float sred[4][64];

  int t = threadIdx.x;
  int w = t >> 6, l = t & 63;
  int q = l >> 4, l16 = l & 15;
  int bid = blockIdx.x;
  int x = bid & 7;
  int j = bid >> 3;
  int nt = j & 7;
  int mt = x * 64 + (j >> 3);
  int row0 = mt * 128;
  int d0 = nt * 128;
  int b = row0 >> 11;
  int wm = w >> 1, wn = w & 1;

  int ar = l >> 3;
  int ac = (l & 7) ^ ar;
  const float* gA[4];
  float* lA[4];
#pragma unroll
  for (int s = 0; s < 4; ++s) {
    gA[s] = value + (size_t)(row0 + 32 * w + 8 * s + ar) * H_SZ + ac * 4;
    lA[s] = Asf + (32 * w + 8 * s) * 32;
  }
  int lr = l >> 2;
  int kc = ((l & 3) ^ ((l >> 3) & 3)) * 8;
  const short* gB0 = wvb + (size_t)(d0 + 32 * w + lr) * H_SZ + kc;
  const short* gB1 = wvb + (size_t)(d0 + 32 * w + 16 + lr) * H_SZ + kc;
  short* lB0 = Bsf + (32 * w) * 32;
  short* lB1 = Bsf + (32 * w + 16) * 32;

  int h7 = l16 & 7;
  int pA0 = ((2 * q) ^ h7) * 4;
  int pA1 = ((2 * q + 1) ^ h7) * 4;
  int posB = (q ^ ((l16 >> 1) & 3)) * 8;

  f32x4 acc[4][4];
#pragma unroll
  for (int i = 0; i < 4; ++i)
#pragma unroll
    for (int jj = 0; jj < 4; ++jj) acc[i][jj] = (f32x4){0.f, 0.f, 0.f, 0.f};

  for (int kt = 0; kt <= 32; ++kt) {
    if (kt < 32) {
      int k0 = kt * 32;
#pragma unroll
      for (int s = 0; s < 4; ++s) ldg_lds16(gA[s] + k0, lA[s]);
      ldg_lds16(gB0 + (size_t)k0, lB0);
      ldg_lds16(gB1 + (size_t)k0, lB1);
    } else {
#pragma unroll
      for (int s = 0; s < 4; ++s)
        ldg_lds16(cff + (size_t)(row0 + 32 * w + 8 * s + ar) * C_SZ + ac * 4, lA[s]);
      ldg_lds16(wlocb + (size_t)(d0 + 32 * w + lr) * C_SZ + kc, lB0);
      ldg_lds16(wlocb + (size_t)(d0 + 32 * w + 16 + lr) * C_SZ + kc, lB1);
    }
    __syncthreads();

    s16x8 a[4], bb[4];
#pragma unroll
    for (int i = 0; i < 4; ++i) {
      const float* rowp = Asf + (wm * 64 + i * 16 + l16) * 32;
      f32x4 f0 = *(const f32x4*)(rowp + pA0);
      f32x4 f1 = *(const f32x4*)(rowp + pA1);
      u32x4 pk;
      pk[0] = pack2(f0[0], f0[1]);
      pk[1] = pack2(f0[2], f0[3]);
      pk[2] = pack2(f1[0], f1[1]);
      pk[3] = pack2(f1[2], f1[3]);
      a[i] = *(s16x8*)&pk;
    }
#pragma unroll
    for (int jj = 0; jj < 4; ++jj)
      bb[jj] = *(const s16x8*)(Bsf + (wn * 64 + jj * 16 + l16) * 32 + posB);
#pragma unroll
    for (int i = 0; i < 4; ++i)
#pragma unroll
      for (int jj = 0; jj < 4; ++jj)
        acc[i][jj] = __builtin_amdgcn_mfma_f32_16x16x32_bf16(a[i], bb[jj], acc[i][jj], 0, 0, 0);
    __syncthreads();
  }

  float qv[4], wv[4];
#pragma unroll
  for (int jj = 0; jj < 4; ++jj) {
    int d = d0 + wn * 64 + jj * 16 + l16;
    qv[jj] = qpb[(size_t)b * DIM_SZ + d];
    wv[jj] = w_score[d];
  }

#pragma unroll
  for (int i = 0; i < 4; ++i) {
#pragma unroll
    for (int r = 0; r < 4; ++r) {
      float part = 0.f;
#pragma unroll
      for (int jj = 0; jj < 4; ++jj)
        part += fast_tanh(acc[i][jj][r] + qv[jj]) * wv[jj];
      part += __shfl_xor(part, 1);
      part += __shfl_xor(part, 2);
      part += __shfl_xor(part, 4);
      part += __shfl_xor(part, 8);
      if (l16 == 0) sred[w][i * 16 + q * 4 + r] = part;
    }
  }
  __syncthreads();
  if (t < 128) {
    int half = t >> 6;
    float v = sred[half * 2][t & 63] + sred[half * 2 + 1][t & 63];
    atomicAdd(&score[row0 + t], v);
  }
}
// ================= end fallback =================

// ---- fused sigmoid-normalize + context partial; grid (32 b, 16 vc) ----
// bf16 value (vb) path: 128 MB instead of 256 MB, LLC-warm after k_score32.
__global__ __launch_bounds__(256) void k_ctx(
    const float* __restrict__ score, const float* __restrict__ b_score,
    const short* __restrict__ vb, float* __restrict__ attn_out,
    float* __restrict__ context) {
  __shared__ float als[VLEN_SZ];
  __shared__ float red[4];
  int b = blockIdx.x, vc = blockIdx.y, t = threadIdx.x;
  float bs = b_score[0];
  float sv[8];
  float lsum = 0.f;
  int v0 = t * 8;
#pragma unroll
  for (int k = 0; k < 8; ++k) {
    float ps = score[(size_t)b * VLEN_SZ + v0 + k] + bs;
    float s = 1.0f / (1.0f + __expf(-ps));
    sv[k] = s;
    lsum += s;
    als[v0 + k] = s;
  }
#pragma unroll
  for (int off = 32; off; off >>= 1) lsum += __shfl_xor(lsum, off, 64);
  if ((t & 63) == 0) red[t >> 6] = lsum;
  __syncthreads();
  float inv = 1.0f / (red[0] + red[1] + red[2] + red[3]);
  if (vc == 0) {
#pragma unroll
    for (int k = 0; k < 8; ++k)
      attn_out[(size_t)b * VLEN_SZ + v0 + k] = sv[k] * inv;
  }

  int h0 = t * 4;
  int vbase = vc * 128;
  const short* vp = vb + ((size_t)b * VLEN_SZ + vbase) * H_SZ + h0;
  const float* av = als + vbase;
  f32x4 acc = (f32x4){0.f, 0.f, 0.f, 0.f};
#pragma unroll 8
  for (int v = 0; v < 128; ++v) {
    s16x4 xv = *(const s16x4*)(vp + (size_t)v * H_SZ);
    float a = av[v];
    acc[0] += a * bf2f(xv[0]); acc[1] += a * bf2f(xv[1]);
    acc[2] += a * bf2f(xv[2]); acc[3] += a * bf2f(xv[3]);
  }
#pragma unroll
  for (int k = 0; k < 4; ++k)
    atomicAdd(&context[(size_t)b * H_SZ + h0 + k], acc[k] * inv);
}

// fp32-value variant for the fallback path
__global__ __launch_bounds__(256) void k_ctx_f32(
    const float* __restrict__ score, const float* __restrict__ b_score,
    const float* __restrict__ value, float* __restrict__ attn_out,
    float* __restrict__ context) {
  __shared__ float als[VLEN_SZ];
  __shared__ float red[4];
  int b = blockIdx.x, vc = blockIdx.y, t = threadIdx.x;
  float bs = b_score[0];
  float sv[8];
  float lsum = 0.f;
  int v0 = t * 8;
#pragma unroll
  for (int k = 0; k < 8; ++k) {
    float ps = score[(size_t)b * VLEN_SZ + v0 + k] + bs;
    float s = 1.0f / (1.0f + __expf(-ps));
    sv[k] = s;
    lsum += s;
    als[v0 + k] = s;
  }
#pragma unroll
  for (int off = 32; off; off >>= 1) lsum += __shfl_xor(lsum, off, 64);
  if ((t & 63) == 0) red[t >> 6] = lsum;
  __syncthreads();
  float inv = 1.0f / (red[0] + red[1] + red[2] + red[3]);
  if (vc == 0) {
#pragma unroll
    for (int k = 0; k < 8; ++k)
      attn_out[(size_t)b * VLEN_SZ + v0 + k] = sv[k] * inv;
  }

  int h0 = t * 4;
  int vbase = vc * 128;
  const float* vp = value + ((size_t)b * VLEN_SZ + vbase) * H_SZ + h0;
  const float* av = als + vbase;
  f32x4 acc = (f32x4){0.f, 0.f, 0.f, 0.f};
#pragma unroll 8
  for (int v = 0; v < 128; ++v) {
    f32x4 xv = *(const f32x4*)(vp + (size_t)v * H_SZ);
    float a = av[v];
    acc[0] += a * xv[0]; acc[1] += a * xv[1];
    acc[2] += a * xv[2]; acc[3] += a * xv[3];
  }
#pragma unroll
  for (int k = 0; k < 4; ++k)
    atomicAdd(&context[(size_t)b * H_SZ + h0 + k], acc[k] * inv);
}

// ---- out[b,h] = b_out[h] + [context|query] . w_out[h,:]; one wave per output ----
__global__ void k_out(const float* __restrict__ context, const float* __restrict__ query,
                      const float* __restrict__ w_out, const float* __restrict__ b_out,
                      float* __restrict__ out) {
  int wid = blockIdx.x * 4 + (threadIdx.x >> 6);
  int lane = threadIdx.x & 63;
  int h = wid >> 5;
  int b = wid & 31;
  const f32x4* w4 = (const f32x4*)(w_out + (size_t)h * 2048);
  const f32x4* c4 = (const f32x4*)(context + (size_t)b * H_SZ);
  const f32x4* q4 = (const f32x4*)(query + (size_t)b * H_SZ);
  float acc = 0.f;
#pragma unroll
  for (int it = 0; it < 8; ++it) {
    int k4 = it * 64 + lane;
    f32x4 w = w4[k4];
    f32x4 c = (k4 < 256) ? c4[k4] : q4[k4 - 256];
    acc += w[0] * c[0] + w[1] * c[1] + w[2] * c[2] + w[3] * c[3];
  }
#pragma unroll
  for (int off = 32; off; off >>= 1) acc += __shfl_xor(acc, off, 64);
  if (lane == 0) out[(size_t)b * H_SZ + h] = acc + b_out[h];
}

extern "C" void kernel_launch(void* const* d_in, const int* in_sizes, int n_in,
                              void* d_out, int out_size, void* d_ws, size_t ws_size,
                              hipStream_t stream) {
  const float* query   = (const float*)d_in[0];
  const float* value   = (const float*)d_in[1];
  const float* prev    = (const float*)d_in[2];
  const float* conv_w  = (const float*)d_in[3];
  const float* conv_b  = (const float*)d_in[4];
  const float* w_loc   = (const float*)d_in[5];
  const float* w_q     = (const float*)d_in[6];
  const float* w_v     = (const float*)d_in[7];
  const float* bias    = (const float*)d_in[8];
  const float* w_score = (const float*)d_in[9];
  const float* b_score = (const float*)d_in[10];
  const float* w_out   = (const float*)d_in[11];
  const float* b_out   = (const float*)d_in[12];

  float* out  = (float*)d_out;                 // (B,1,H) = 32768 floats
  float* attn = out + B_SZ * H_SZ;             // (B,V)   = 65536 floats

  char* ws = (char*)d_ws;
  float* score   = (float*)(ws);               // 256 KB
  float* qpb     = (float*)(ws + (256 << 10)); // 128 KB
  float* context = (float*)(ws + (384 << 10)); // 128 KB
  short* wvb     = (short*)(ws + (512 << 10)); // 2 MB   bf16 w_v
  short* wlocb   = (short*)(ws + (2560 << 10));// 64 KB  bf16 w_loc

  size_t need = ((size_t)16 << 20) + ((size_t)128 << 20);  // vb ends at 144 MB
  if (ws_size >= need) {
    short* cfb = (short*)(ws + (3 << 20));     // 4 MB   bf16 conv features
    short* vb  = (short*)(ws + ((size_t)16 << 20));  // 128 MB bf16 value
    k_prep<<<34432, 256, 0, stream>>>(query, w_q, bias, prev, conv_w, conv_b,
                                      w_loc, w_v, value, qpb, cfb, wlocb, wvb, vb,
                                      score, context);
    k_score32<<<4096, 256, 0, stream>>>(vb, wvb, wlocb, cfb, qpb, w_score, score);
    k_ctx<<<dim3(B_SZ, 16), 256, 0, stream>>>(score, b_score, vb, attn, context);
  } else {
    float* cff = (float*)(ws + (3 << 20));     // 8 MB   fp32 conv features
    k_prep_f32<<<9600, 256, 0, stream>>>(query, w_q, bias, prev, conv_w, conv_b,
                                         w_loc, w_v, qpb, cff, wlocb, wvb, score, context);
    k_score_f32<<<4096, 256, 0, stream>>>(value, wvb, wlocb, cff, qpb, w_score, score);
    k_ctx_f32<<<dim3(B_SZ, 16), 256, 0, stream>>>(score, b_score, value, attn, context);
  }
  k_out<<<(B_SZ * H_SZ) / 4, 256, 0, stream>>>(context, query, w_out, b_out, out);
}

// Round 6
// 625.317 us; speedup vs baseline: 1.1438x; 1.1438x over previous
//
#include <hip/hip_runtime.h>
#include <hip/hip_bf16.h>
#include <math.h>

#define B_SZ 32
#define VLEN_SZ 2048
#define H_SZ 1024
#define DIM_SZ 1024
#define C_SZ 32

typedef float f32x4 __attribute__((ext_vector_type(4)));
typedef short s16x8 __attribute__((ext_vector_type(8)));
typedef short s16x4 __attribute__((ext_vector_type(4)));
typedef unsigned int u32x4 __attribute__((ext_vector_type(4)));

__device__ __forceinline__ short f2bf(float f) {
  unsigned u = __float_as_uint(f);
  u = (u + 0x7fffu + ((u >> 16) & 1u)) >> 16;  // RNE
  return (short)u;
}

__device__ __forceinline__ float bf2f(short s) {
  return __uint_as_float(((unsigned)(unsigned short)s) << 16);
}

// pack hi16(a), hi16(b) -> (bf16(b)<<16)|bf16(a)  [truncation], 1 instr
__device__ __forceinline__ unsigned pack2(float a, float b) {
  return __builtin_amdgcn_perm(__float_as_uint(b), __float_as_uint(a), 0x07060302u);
}

__device__ __forceinline__ float fast_tanh(float x) {
  float z = __expf(2.0f * x);
  return 1.0f - 2.0f / (z + 1.0f);
}

// async 16B global -> LDS. LDS base MUST be wave-uniform (HW adds lane*16).
__device__ __forceinline__ void ldg_lds16(const void* g, void* l) {
  __builtin_amdgcn_global_load_lds(
      (const __attribute__((address_space(1))) unsigned int*)g,
      (__attribute__((address_space(3))) unsigned int*)l, 16, 0, 0);
}

// ---- fused prep (round-5 proven): qpb + conv(bf16) + casts + value->bf16 ----
// role by block range:
//   [0,256)        qp[b,d]: one WAVE per d, loop over b (w_q read exactly once)
//   [256,512)      conv features cfb[b,v,c] bf16
//   [512,544)      w_loc -> bf16
//   [544,1568)     w_v   -> bf16
//   [1568,1632)    zero score
//   [1632,1664)    zero context
//   [1664,34432)   value -> bf16 (8 floats/thread, s16x8 stores)
__global__ __launch_bounds__(256) void k_prep(
    const float* __restrict__ query, const float* __restrict__ w_q,
    const float* __restrict__ bias, const float* __restrict__ prev,
    const float* __restrict__ conv_w, const float* __restrict__ conv_b,
    const float* __restrict__ w_loc, const float* __restrict__ w_v,
    const float* __restrict__ value,
    float* __restrict__ qpb, short* __restrict__ cfb, short* __restrict__ wlocb,
    short* __restrict__ wvb, short* __restrict__ vb,
    float* __restrict__ score, float* __restrict__ context) {
  int bid = blockIdx.x;
  int t = threadIdx.x;
  if (bid < 256) {
    int d = bid * 4 + (t >> 6);      // one wave per output column d
    int l = t & 63;
    const f32x4* w4 = (const f32x4*)(w_q + (size_t)d * H_SZ);
    f32x4 wq[4];
#pragma unroll
    for (int it = 0; it < 4; ++it) wq[it] = w4[it * 64 + l];
    float bd = bias[d];
    for (int b = 0; b < B_SZ; ++b) {
      const f32x4* q4 = (const f32x4*)(query + (size_t)b * H_SZ);
      float acc = 0.f;
#pragma unroll
      for (int it = 0; it < 4; ++it) {
        f32x4 a = q4[it * 64 + l];
        acc += a[0] * wq[it][0] + a[1] * wq[it][1] + a[2] * wq[it][2] + a[3] * wq[it][3];
      }
#pragma unroll
      for (int off = 32; off; off >>= 1) acc += __shfl_xor(acc, off, 64);
      if (l == 0) qpb[(size_t)b * DIM_SZ + d] = acc + bd;
    }
  } else if (bid < 512) {
    int r = (bid - 256) * 256 + t;  // row index b*VLEN+v
    int v = r & (VLEN_SZ - 1);
    float p0 = prev[r];
    float pm = (v > 0) ? prev[r - 1] : 0.f;
    float pp = (v < VLEN_SZ - 1) ? prev[r + 1] : 0.f;
    float o[C_SZ];
#pragma unroll
    for (int c = 0; c < C_SZ; ++c)
      o[c] = conv_b[c] + pm * conv_w[c * 3 + 0] + p0 * conv_w[c * 3 + 1] + pp * conv_w[c * 3 + 2];
    s16x8* dst = (s16x8*)(cfb + (size_t)r * C_SZ);
#pragma unroll
    for (int g = 0; g < 4; ++g) {
      s16x8 pk;
#pragma unroll
      for (int e = 0; e < 8; ++e) pk[e] = f2bf(o[8 * g + e]);
      dst[g] = pk;
    }
  } else if (bid < 544) {
    int i = (bid - 512) * 256 + t;  // n4 = 8192
    f32x4 v = ((const f32x4*)w_loc)[i];
    s16x4 o;
    o[0] = f2bf(v[0]); o[1] = f2bf(v[1]); o[2] = f2bf(v[2]); o[3] = f2bf(v[3]);
    ((s16x4*)wlocb)[i] = o;
  } else if (bid < 1568) {
    int i = (bid - 544) * 256 + t;  // n4 = 262144
    f32x4 v = ((const f32x4*)w_v)[i];
    s16x4 o;
    o[0] = f2bf(v[0]); o[1] = f2bf(v[1]); o[2] = f2bf(v[2]); o[3] = f2bf(v[3]);
    ((s16x4*)wvb)[i] = o;
  } else if (bid < 1632) {
    int i = (bid - 1568) * 256 + t;  // 16384 f32x4
    ((f32x4*)score)[i] = (f32x4){0.f, 0.f, 0.f, 0.f};
  } else if (bid < 1664) {
    int i = (bid - 1632) * 256 + t;  // 8192 f32x4
    ((f32x4*)context)[i] = (f32x4){0.f, 0.f, 0.f, 0.f};
  } else {
    // value (fp32, 67.1M) -> bf16. 8 floats/thread: read 32B, write 16B.
    size_t i = (size_t)(bid - 1664) * 256 + t;  // 0 .. 8388607
    const f32x4* src = (const f32x4*)value;
    f32x4 v0 = src[2 * i], v1 = src[2 * i + 1];
    s16x8 o;
    o[0] = f2bf(v0[0]); o[1] = f2bf(v0[1]); o[2] = f2bf(v0[2]); o[3] = f2bf(v0[3]);
    o[4] = f2bf(v1[0]); o[5] = f2bf(v1[1]); o[6] = f2bf(v1[2]); o[7] = f2bf(v1[3]);
    ((s16x8*)vb)[i] = o;
  }
}

// ---- main fused kernel (round-1 proven, 201 us): 128x128 tile, pure bf16 ----
// Both A (vb) and B (wvb) tiles are 128 rows x 32 bf16 (64 B/row), staged
// via global_load_lds (2 instrs/wave/operand, 16 rows each). Swizzle: row r,
// 16B-chunk c stored at position c ^ ((r>>1)&3) -> 2-way-aliased (free) reads.
// XCD-aware 1-D grid 4096: x=bid&7 owns mt range, nt consecutive -> L2 reuse.
__global__ __launch_bounds__(256, 4) void k_score(
    const short* __restrict__ vb, const short* __restrict__ wvb,
    const short* __restrict__ wlocb, const short* __restrict__ cfb,
    const float* __restrict__ qpb, const float* __restrict__ w_score,
    float* __restrict__ score) {
  __shared__ short As[128 * 32];   // 8 KB bf16
  __shared__ short Bs[128 * 32];   // 8 KB bf16
  __shared__ float sred[4][64];

  int t = threadIdx.x;
  int w = t >> 6, l = t & 63;
  int q = l >> 4, l16 = l & 15;
  int bid = blockIdx.x;
  int x = bid & 7;
  int j = bid >> 3;
  int nt = j & 7;                  // 0..7
  int mt = x * 64 + (j >> 3);      // 0..511
  int row0 = mt * 128;             // global row base (b*VLEN+v)
  int d0 = nt * 128;
  int b = row0 >> 11;              // VLEN = 2048
  int wm = w >> 1, wn = w & 1;

  // staging: per wave 32 rows per operand, 2 instrs (16 rows x 64 B each).
  // lane l -> row l>>2, pos l&3 (16B units), content chunk (l&3)^((l>>3)&3).
  int lr = l >> 2;
  int kc = ((l & 3) ^ ((l >> 3) & 3)) * 8;  // content chunk, bf16 offset
  const short* gA0 = vb + (size_t)(row0 + 32 * w + lr) * H_SZ + kc;
  const short* gA1 = vb + (size_t)(row0 + 32 * w + 16 + lr) * H_SZ + kc;
  const short* gB0 = wvb + (size_t)(d0 + 32 * w + lr) * H_SZ + kc;
  const short* gB1 = wvb + (size_t)(d0 + 32 * w + 16 + lr) * H_SZ + kc;
  short* lA0 = As + (32 * w) * 32;
  short* lA1 = As + (32 * w + 16) * 32;
  short* lB0 = Bs + (32 * w) * 32;
  short* lB1 = Bs + (32 * w + 16) * 32;

  // fragment read: row r, k-chunk q lives at 16B-position q ^ ((r>>1)&3);
  // (r>>1)&3 == (l16>>1)&3 for all frag rows (i*16 offsets are mod-4 zero).
  int posf = (q ^ ((l16 >> 1) & 3)) * 8;    // bf16 offset

  f32x4 acc[4][4];
#pragma unroll
  for (int i = 0; i < 4; ++i)
#pragma unroll
    for (int jj = 0; jj < 4; ++jj) acc[i][jj] = (f32x4){0.f, 0.f, 0.f, 0.f};

  for (int kt = 0; kt <= 32; ++kt) {
    if (kt < 32) {
      int k0 = kt * 32;
      ldg_lds16(gA0 + k0, lA0);
      ldg_lds16(gA1 + k0, lA1);
      ldg_lds16(gB0 + k0, lB0);
      ldg_lds16(gB1 + k0, lB1);
    } else {
      // location-feature K-step: A = cfb (bf16, row = 32 = one tile row), B = w_loc
      ldg_lds16(cfb + (size_t)(row0 + 32 * w + lr) * C_SZ + kc, lA0);
      ldg_lds16(cfb + (size_t)(row0 + 32 * w + 16 + lr) * C_SZ + kc, lA1);
      ldg_lds16(wlocb + (size_t)(d0 + 32 * w + lr) * C_SZ + kc, lB0);
      ldg_lds16(wlocb + (size_t)(d0 + 32 * w + 16 + lr) * C_SZ + kc, lB1);
    }
    __syncthreads();

    s16x8 a[4], bb[4];
#pragma unroll
    for (int i = 0; i < 4; ++i)
      a[i] = *(const s16x8*)(As + (wm * 64 + i * 16 + l16) * 32 + posf);
#pragma unroll
    for (int jj = 0; jj < 4; ++jj)
      bb[jj] = *(const s16x8*)(Bs + (wn * 64 + jj * 16 + l16) * 32 + posf);
#pragma unroll
    for (int i = 0; i < 4; ++i)
#pragma unroll
      for (int jj = 0; jj < 4; ++jj)
        acc[i][jj] = __builtin_amdgcn_mfma_f32_16x16x32_bf16(a[i], bb[jj], acc[i][jj], 0, 0, 0);
    __syncthreads();
  }

  // epilogue: e = tanh(acc + qp[d]) (qp includes bias), score += e.w_score
  float qv[4], wv[4];
#pragma unroll
  for (int jj = 0; jj < 4; ++jj) {
    int d = d0 + wn * 64 + jj * 16 + l16;
    qv[jj] = qpb[(size_t)b * DIM_SZ + d];
    wv[jj] = w_score[d];
  }

#pragma unroll
  for (int i = 0; i < 4; ++i) {
#pragma unroll
    for (int r = 0; r < 4; ++r) {
      float part = 0.f;
#pragma unroll
      for (int jj = 0; jj < 4; ++jj)
        part += fast_tanh(acc[i][jj][r] + qv[jj]) * wv[jj];
      part += __shfl_xor(part, 1);
      part += __shfl_xor(part, 2);
      part += __shfl_xor(part, 4);
      part += __shfl_xor(part, 8);
      if (l16 == 0) sred[w][i * 16 + q * 4 + r] = part;
    }
  }
  __syncthreads();
  if (t < 128) {
    int half = t >> 6;
    float v = sred[half * 2][t & 63] + sred[half * 2 + 1][t & 63];
    atomicAdd(&score[row0 + t], v);
  }
}

// ================= fallback path (small workspace): previous proven kernels =================
__global__ __launch_bounds__(256) void k_prep_f32(
    const float* __restrict__ query, const float* __restrict__ w_q,
    const float* __restrict__ bias, const float* __restrict__ prev,
    const float* __restrict__ conv_w, const float* __restrict__ conv_b,
    const float* __restrict__ w_loc, const float* __restrict__ w_v,
    float* __restrict__ qpb, float* __restrict__ cff, short* __restrict__ wlocb,
    short* __restrict__ wvb, float* __restrict__ score, float* __restrict__ context) {
  int bid = blockIdx.x;
  int t = threadIdx.x;
  if (bid < 8192) {
    int wid = bid * 4 + (t >> 6);
    int lane = t & 63;
    int d = wid >> 5;
    int b = wid & 31;
    const f32x4* q4 = (const f32x4*)(query + (size_t)b * H_SZ);
    const f32x4* w4 = (const f32x4*)(w_q + (size_t)d * H_SZ);
    float acc = 0.f;
#pragma unroll
    for (int it = 0; it < 4; ++it) {
      int k = it * 64 + lane;
      f32x4 a = q4[k], w = w4[k];
      acc += a[0] * w[0] + a[1] * w[1] + a[2] * w[2] + a[3] * w[3];
    }
#pragma unroll
    for (int off = 32; off; off >>= 1) acc += __shfl_xor(acc, off, 64);
    if (lane == 0) qpb[(size_t)b * DIM_SZ + d] = acc + bias[d];
  } else if (bid < 8448) {
    int r = (bid - 8192) * 256 + t;
    int v = r & (VLEN_SZ - 1);
    float p0 = prev[r];
    float pm = (v > 0) ? prev[r - 1] : 0.f;
    float pp = (v < VLEN_SZ - 1) ? prev[r + 1] : 0.f;
    float o[C_SZ];
#pragma unroll
    for (int c = 0; c < C_SZ; ++c)
      o[c] = conv_b[c] + pm * conv_w[c * 3 + 0] + p0 * conv_w[c * 3 + 1] + pp * conv_w[c * 3 + 2];
    f32x4* dst = (f32x4*)(cff + (size_t)r * C_SZ);
#pragma unroll
    for (int g = 0; g < 8; ++g)
      dst[g] = (f32x4){o[4 * g], o[4 * g + 1], o[4 * g + 2], o[4 * g + 3]};
  } else if (bid < 8480) {
    int i = (bid - 8448) * 256 + t;
    f32x4 v = ((const f32x4*)w_loc)[i];
    s16x4 o;
    o[0] = f2bf(v[0]); o[1] = f2bf(v[1]); o[2] = f2bf(v[2]); o[3] = f2bf(v[3]);
    ((s16x4*)wlocb)[i] = o;
  } else if (bid < 9504) {
    int i = (bid - 8480) * 256 + t;
    f32x4 v = ((const f32x4*)w_v)[i];
    s16x4 o;
    o[0] = f2bf(v[0]); o[1] = f2bf(v[1]); o[2] = f2bf(v[2]); o[3] = f2bf(v[3]);
    ((s16x4*)wvb)[i] = o;
  } else if (bid < 9568) {
    int i = (bid - 9504) * 256 + t;
    ((f32x4*)score)[i] = (f32x4){0.f, 0.f, 0.f, 0.f};
  } else {
    int i = (bid - 9568) * 256 + t;
    ((f32x4*)context)[i] = (f32x4){0.f, 0.f, 0.f, 0.f};
  }
}

__global__ __launch_bounds__(256, 4) void k_score_f32(
    const float* __restrict__ value, const short* __restrict__ wvb,
    const short* __restrict__ wlocb, const float* __restrict__ cff,
    const float* __restrict__ qpb, const float* __restrict__ w_score,
    float* __restrict__ score) {
  __shared__ float Asf[128 * 32];
  __shared__ short Bsf[128 * 32];
  __shared__ float sred[4][64];

  int t = threadIdx.x;
  int w = t >> 6, l = t & 63;
  int q = l >> 4, l16 = l & 15;
  int bid = blockIdx.x;
  int x = bid & 7;
  int j = bid >> 3;
  int nt = j & 7;
  int mt = x * 64 + (j >> 3);
  int row0 = mt * 128;
  int d0 = nt * 128;
  int b = row0 >> 11;
  int wm = w >> 1, wn = w & 1;

  int ar = l >> 3;
  int ac = (l & 7) ^ ar;
  const float* gA[4];
  float* lA[4];
#pragma unroll
  for (int s = 0; s < 4; ++s) {
    gA[s] = value + (size_t)(row0 + 32 * w + 8 * s + ar) * H_SZ + ac * 4;
    lA[s] = Asf + (32 * w + 8 * s) * 32;
  }
  int lr = l >> 2;
  int kc = ((l & 3) ^ ((l >> 3) & 3)) * 8;
  const short* gB0 = wvb + (size_t)(d0 + 32 * w + lr) * H_SZ + kc;
  const short* gB1 = wvb + (size_t)(d0 + 32 * w + 16 + lr) * H_SZ + kc;
  short* lB0 = Bsf + (32 * w) * 32;
  short* lB1 = Bsf + (32 * w + 16) * 32;

  int h7 = l16 & 7;
  int pA0 = ((2 * q) ^ h7) * 4;
  int pA1 = ((2 * q + 1) ^ h7) * 4;
  int posB = (q ^ ((l16 >> 1) & 3)) * 8;

  f32x4 acc[4][4];
#pragma unroll
  for (int i = 0; i < 4; ++i)
#pragma unroll
    for (int jj = 0; jj < 4; ++jj) acc[i][jj] = (f32x4){0.f, 0.f, 0.f, 0.f};

  for (int kt = 0; kt <= 32; ++kt) {
    if (kt < 32) {
      int k0 = kt * 32;
#pragma unroll
      for (int s = 0; s < 4; ++s) ldg_lds16(gA[s] + k0, lA[s]);
      ldg_lds16(gB0 + (size_t)k0, lB0);
      ldg_lds16(gB1 + (size_t)k0, lB1);
    } else {
#pragma unroll
      for (int s = 0; s < 4; ++s)
        ldg_lds16(cff + (size_t)(row0 + 32 * w + 8 * s + ar) * C_SZ + ac * 4, lA[s]);
      ldg_lds16(wlocb + (size_t)(d0 + 32 * w + lr) * C_SZ + kc, lB0);
      ldg_lds16(wlocb + (size_t)(d0 + 32 * w + 16 + lr) * C_SZ + kc, lB1);
    }
    __syncthreads();

    s16x8 a[4], bb[4];
#pragma unroll
    for (int i = 0; i < 4; ++i) {
      const float* rowp = Asf + (wm * 64 + i * 16 + l16) * 32;
      f32x4 f0 = *(const f32x4*)(rowp + pA0);
      f32x4 f1 = *(const f32x4*)(rowp + pA1);
      u32x4 pk;
      pk[0] = pack2(f0[0], f0[1]);
      pk[1] = pack2(f0[2], f0[3]);
      pk[2] = pack2(f1[0], f1[1]);
      pk[3] = pack2(f1[2], f1[3]);
      a[i] = *(s16x8*)&pk;
    }
#pragma unroll
    for (int jj = 0; jj < 4; ++jj)
      bb[jj] = *(const s16x8*)(Bsf + (wn * 64 + jj * 16 + l16) * 32 + posB);
#pragma unroll
    for (int i = 0; i < 4; ++i)
#pragma unroll
      for (int jj = 0; jj < 4; ++jj)
        acc[i][jj] = __builtin_amdgcn_mfma_f32_16x16x32_bf16(a[i], bb[jj], acc[i][jj], 0, 0, 0);
    __syncthreads();
  }

  float qv[4], wv[4];
#pragma unroll
  for (int jj = 0; jj < 4; ++jj) {
    int d = d0 + wn * 64 + jj * 16 + l16;
    qv[jj] = qpb[(size_t)b * DIM_SZ + d];
    wv[jj] = w_score[d];
  }

#pragma unroll
  for (int i = 0; i < 4; ++i) {
#pragma unroll
    for (int r = 0; r < 4; ++r) {
      float part = 0.f;
#pragma unroll
      for (int jj = 0; jj < 4; ++jj)
        part += fast_tanh(acc[i][jj][r] + qv[jj]) * wv[jj];
      part += __shfl_xor(part, 1);
      part += __shfl_xor(part, 2);
      part += __shfl_xor(part, 4);
      part += __shfl_xor(part, 8);
      if (l16 == 0) sred[w][i * 16 + q * 4 + r] = part;
    }
  }
  __syncthreads();
  if (t < 128) {
    int half = t >> 6;
    float v = sred[half * 2][t & 63] + sred[half * 2 + 1][t & 63];
    atomicAdd(&score[row0 + t], v);
  }
}
// ================= end fallback =================

// ---- fused sigmoid-normalize + context partial; grid (32 b, 16 vc) ----
// bf16 value (vb) path: 128 MB instead of 256 MB, LLC-warm after k_score.
__global__ __launch_bounds__(256) void k_ctx(
    const float* __restrict__ score, const float* __restrict__ b_score,
    const short* __restrict__ vb, float* __restrict__ attn_out,
    float* __restrict__ context) {
  __shared__ float als[VLEN_SZ];
  __shared__ float red[4];
  int b = blockIdx.x, vc = blockIdx.y, t = threadIdx.x;
  float bs = b_score[0];
  float sv[8];
  float lsum = 0.f;
  int v0 = t * 8;
#pragma unroll
  for (int k = 0; k < 8; ++k) {
    float ps = score[(size_t)b * VLEN_SZ + v0 + k] + bs;
    float s = 1.0f / (1.0f + __expf(-ps));
    sv[k] = s;
    lsum += s;
    als[v0 + k] = s;
  }
#pragma unroll
  for (int off = 32; off; off >>= 1) lsum += __shfl_xor(lsum, off, 64);
  if ((t & 63) == 0) red[t >> 6] = lsum;
  __syncthreads();
  float inv = 1.0f / (red[0] + red[1] + red[2] + red[3]);
  if (vc == 0) {
#pragma unroll
    for (int k = 0; k < 8; ++k)
      attn_out[(size_t)b * VLEN_SZ + v0 + k] = sv[k] * inv;
  }

  int h0 = t * 4;
  int vbase = vc * 128;
  const short* vp = vb + ((size_t)b * VLEN_SZ + vbase) * H_SZ + h0;
  const float* av = als + vbase;
  f32x4 acc = (f32x4){0.f, 0.f, 0.f, 0.f};
#pragma unroll 8
  for (int v = 0; v < 128; ++v) {
    s16x4 xv = *(const s16x4*)(vp + (size_t)v * H_SZ);
    float a = av[v];
    acc[0] += a * bf2f(xv[0]); acc[1] += a * bf2f(xv[1]);
    acc[2] += a * bf2f(xv[2]); acc[3] += a * bf2f(xv[3]);
  }
#pragma unroll
  for (int k = 0; k < 4; ++k)
    atomicAdd(&context[(size_t)b * H_SZ + h0 + k], acc[k] * inv);
}

// fp32-value variant for the fallback path
__global__ __launch_bounds__(256) void k_ctx_f32(
    const float* __restrict__ score, const float* __restrict__ b_score,
    const float* __restrict__ value, float* __restrict__ attn_out,
    float* __restrict__ context) {
  __shared__ float als[VLEN_SZ];
  __shared__ float red[4];
  int b = blockIdx.x, vc = blockIdx.y, t = threadIdx.x;
  float bs = b_score[0];
  float sv[8];
  float lsum = 0.f;
  int v0 = t * 8;
#pragma unroll
  for (int k = 0; k < 8; ++k) {
    float ps = score[(size_t)b * VLEN_SZ + v0 + k] + bs;
    float s = 1.0f / (1.0f + __expf(-ps));
    sv[k] = s;
    lsum += s;
    als[v0 + k] = s;
  }
#pragma unroll
  for (int off = 32; off; off >>= 1) lsum += __shfl_xor(lsum, off, 64);
  if ((t & 63) == 0) red[t >> 6] = lsum;
  __syncthreads();
  float inv = 1.0f / (red[0] + red[1] + red[2] + red[3]);
  if (vc == 0) {
#pragma unroll
    for (int k = 0; k < 8; ++k)
      attn_out[(size_t)b * VLEN_SZ + v0 + k] = sv[k] * inv;
  }

  int h0 = t * 4;
  int vbase = vc * 128;
  const float* vp = value + ((size_t)b * VLEN_SZ + vbase) * H_SZ + h0;
  const float* av = als + vbase;
  f32x4 acc = (f32x4){0.f, 0.f, 0.f, 0.f};
#pragma unroll 8
  for (int v = 0; v < 128; ++v) {
    f32x4 xv = *(const f32x4*)(vp + (size_t)v * H_SZ);
    float a = av[v];
    acc[0] += a * xv[0]; acc[1] += a * xv[1];
    acc[2] += a * xv[2]; acc[3] += a * xv[3];
  }
#pragma unroll
  for (int k = 0; k < 4; ++k)
    atomicAdd(&context[(size_t)b * H_SZ + h0 + k], acc[k] * inv);
}

// ---- out[b,h] = b_out[h] + [context|query] . w_out[h,:]; one wave per output ----
__global__ void k_out(const float* __restrict__ context, const float* __restrict__ query,
                      const float* __restrict__ w_out, const float* __restrict__ b_out,
                      float* __restrict__ out) {
  int wid = blockIdx.x * 4 + (threadIdx.x >> 6);
  int lane = threadIdx.x & 63;
  int h = wid >> 5;
  int b = wid & 31;
  const f32x4* w4 = (const f32x4*)(w_out + (size_t)h * 2048);
  const f32x4* c4 = (const f32x4*)(context + (size_t)b * H_SZ);
  const f32x4* q4 = (const f32x4*)(query + (size_t)b * H_SZ);
  float acc = 0.f;
#pragma unroll
  for (int it = 0; it < 8; ++it) {
    int k4 = it * 64 + lane;
    f32x4 w = w4[k4];
    f32x4 c = (k4 < 256) ? c4[k4] : q4[k4 - 256];
    acc += w[0] * c[0] + w[1] * c[1] + w[2] * c[2] + w[3] * c[3];
  }
#pragma unroll
  for (int off = 32; off; off >>= 1) acc += __shfl_xor(acc, off, 64);
  if (lane == 0) out[(size_t)b * H_SZ + h] = acc + b_out[h];
}

extern "C" void kernel_launch(void* const* d_in, const int* in_sizes, int n_in,
                              void* d_out, int out_size, void* d_ws, size_t ws_size,
                              hipStream_t stream) {
  const float* query   = (const float*)d_in[0];
  const float* value   = (const float*)d_in[1];
  const float* prev    = (const float*)d_in[2];
  const float* conv_w  = (const float*)d_in[3];
  const float* conv_b  = (const float*)d_in[4];
  const float* w_loc   = (const float*)d_in[5];
  const float* w_q     = (const float*)d_in[6];
  const float* w_v     = (const float*)d_in[7];
  const float* bias    = (const float*)d_in[8];
  const float* w_score = (const float*)d_in[9];
  const float* b_score = (const float*)d_in[10];
  const float* w_out   = (const float*)d_in[11];
  const float* b_out   = (const float*)d_in[12];

  float* out  = (float*)d_out;                 // (B,1,H) = 32768 floats
  float* attn = out + B_SZ * H_SZ;             // (B,V)   = 65536 floats

  char* ws = (char*)d_ws;
  float* score   = (float*)(ws);               // 256 KB
  float* qpb     = (float*)(ws + (256 << 10)); // 128 KB
  float* context = (float*)(ws + (384 << 10)); // 128 KB
  short* wvb     = (short*)(ws + (512 << 10)); // 2 MB   bf16 w_v
  short* wlocb   = (short*)(ws + (2560 << 10));// 64 KB  bf16 w_loc

  size_t need = ((size_t)16 << 20) + ((size_t)128 << 20);  // vb ends at 144 MB
  if (ws_size >= need) {
    short* cfb = (short*)(ws + (3 << 20));     // 4 MB   bf16 conv features
    short* vb  = (short*)(ws + ((size_t)16 << 20));  // 128 MB bf16 value
    k_prep<<<34432, 256, 0, stream>>>(query, w_q, bias, prev, conv_w, conv_b,
                                      w_loc, w_v, value, qpb, cfb, wlocb, wvb, vb,
                                      score, context);
    k_score<<<4096, 256, 0, stream>>>(vb, wvb, wlocb, cfb, qpb, w_score, score);
    k_ctx<<<dim3(B_SZ, 16), 256, 0, stream>>>(score, b_score, vb, attn, context);
  } else {
    float* cff = (float*)(ws + (3 << 20));     // 8 MB   fp32 conv features
    k_prep_f32<<<9600, 256, 0, stream>>>(query, w_q, bias, prev, conv_w, conv_b,
                                         w_loc, w_v, qpb, cff, wlocb, wvb, score, context);
    k_score_f32<<<4096, 256, 0, stream>>>(value, wvb, wlocb, cff, qpb, w_score, score);
    k_ctx_f32<<<dim3(B_SZ, 16), 256, 0, stream>>>(score, b_score, value, attn, context);
  }
  k_out<<<(B_SZ * H_SZ) / 4, 256, 0, stream>>>(context, query, w_out, b_out, out);
}